// Round 6
// baseline (292.529 us; speedup 1.0000x reference)
//
#include <hip/hip_runtime.h>
#include <hip/hip_bf16.h>

// B=2,S=2048 -> T=4096 tokens; D=1024; N=64 experts; R=64; TOP_K=2.
// Inputs runtime-detected f32 vs bf16 (measured: f32). Outputs f32 flat:
// [0,262144) proj; [262144,270336) idx; [270336,278528) w.
// R15: R14 won (126.1us; egemm+combine now below the 44us fill in top-5).
// Remaining controllable term: score 43us at VALUBusy 14.5% => ~85% stall
// (x loads are HBM-latency exposed: 1-chunk prefetch slack ~500cy < 900cy,
// 2 barriers/chunk, 8 waves/CU). Fix: double-buffered LDS (1 barrier/chunk)
// + 3-deep register prefetch (issue chunk c at iter c-3, consume at c-1 =>
// ~1200cy slack), fully unrolled so prefetch-set indices are static.
// Compute core, egemm, combine unchanged from the passing R14 build.
// Harness d_ws poison fill (~44us) untouchable.
// d_ws: f32 w[8192] (32KB); int cnt[64]; int list[64*1024] (256KB);
//       P f32[8192][8][64] @ +1MB (16MB).

typedef unsigned short u16;
typedef unsigned int u32;
typedef __attribute__((ext_vector_type(8))) short short8;
typedef __attribute__((ext_vector_type(4))) float f32x4;

__device__ __forceinline__ float bf2f(u16 u) {
    u32 v = ((u32)u) << 16; float f; __builtin_memcpy(&f, &v, 4); return f;
}
__device__ __forceinline__ u16 f2bf(float f) {  // RNE
    u32 u; __builtin_memcpy(&u, &f, 4);
    u32 r = u + 0x7fff + ((u >> 16) & 1);
    return (u16)(r >> 16);
}
__device__ __forceinline__ u32 pack2(float a, float b) {
    return ((u32)f2bf(b) << 16) | (u32)f2bf(a);
}

#define T_TOKENS 4096
#define DDIM 1024
#define NEXP 64
#define RDIM 64
#define LCAP 1024
#define OUT_IDX_OFF 262144
#define OUT_W_OFF 270336

struct LdBF {
    const u16* p;
    __device__ __forceinline__ float4 ld4(size_t i) const {
        ushort4 v = *(const ushort4*)(p + i);
        return make_float4(bf2f(v.x), bf2f(v.y), bf2f(v.z), bf2f(v.w));
    }
    __device__ __forceinline__ float ld1(size_t i) const { return bf2f(p[i]); }
};
struct LdF32 {
    const float* p;
    __device__ __forceinline__ float4 ld4(size_t i) const { return *(const float4*)(p + i); }
    __device__ __forceinline__ float ld1(size_t i) const { return p[i]; }
};

// in-block dtype probe: 1 if f32, 0 if bf16 (all blocks same verdict).
__device__ __forceinline__ int detect_f32(const u16* x, int* lds_cnt) {
    if (threadIdx.x == 0) *lds_cnt = 0;
    __syncthreads();
    if (threadIdx.x < 256) {
        unsigned e = (x[threadIdx.x] >> 7) & 0xFF;
        if (e >= 0x68 && e <= 0x88) atomicAdd(lds_cnt, 1);
    }
    __syncthreads();
    int f = (*lds_cnt < 200) ? 1 : 0;
    __syncthreads();
    return f;
}

// ---------------- Kernel A: score GEMM + top2 + softmax + expert lists ----
// 512 blocks x 256 thr; 8 tokens/block; K-chunks of 64, order rotated by
// blockIdx&15. Double-buffered LDS (1 barrier/chunk) + 3-deep register
// prefetch: chunk c issued at iter c-3, LDS-written at iter c-1, computed
// at iter c. Fully unrolled (static prefetch-set indices; runs once/block).
// Lane: tg=lane&1 (tokens tg+2mi, mi<4), eg=(lane>>1)&7 (experts eg+8ei,
// ei<8), kql=(lane>>4)&3; k-quad per chunk dd = 4*kql + 16*wv (proven).
#define SC_ISSUE(chunk, s)                                                       \
    {                                                                            \
        int kn_ = (((chunk) + kc0) & 15) * 64;                                   \
        if (tid < 128) px[s] = xld.ld4((t0 + sm) * DDIM + kn_ + sd4);            \
        _Pragma("unroll")                                                        \
        for (int h = 0; h < 4; ++h) {                                            \
            int i4 = tid + h * 256;                                              \
            pw[s][h] = rwld.ld4((size_t)(i4 >> 4) * DDIM + kn_ + (i4 & 15) * 4); \
        }                                                                        \
    }

#define SC_WRITEBUF(buf, s)                                                      \
    {                                                                            \
        float* xsb_ = xs + (buf) * (8 * 68);                                     \
        float* wtb_ = wt + (buf) * (64 * 68);                                    \
        if (tid < 128) *(float4*)&xsb_[sm * 68 + sd4] = px[s];                   \
        _Pragma("unroll")                                                        \
        for (int h = 0; h < 4; ++h) {                                            \
            int i4 = tid + h * 256;                                              \
            *(float4*)&wtb_[(i4 >> 4) * 68 + (i4 & 15) * 4] = pw[s][h];          \
        }                                                                        \
    }

#define SC_COMPUTE(buf)                                                          \
    {                                                                            \
        const float* xsb_ = xs + (buf) * (8 * 68);                               \
        const float* wtb_ = wt + (buf) * (64 * 68);                              \
        float4 xv[4], wv4[8];                                                    \
        _Pragma("unroll")                                                        \
        for (int mi = 0; mi < 4; ++mi)                                           \
            xv[mi] = *(const float4*)&xsb_[(tg + 2 * mi) * 68 + dd];             \
        _Pragma("unroll")                                                        \
        for (int ei = 0; ei < 8; ++ei)                                           \
            wv4[ei] = *(const float4*)&wtb_[(eg + 8 * ei) * 68 + dd];            \
        _Pragma("unroll")                                                        \
        for (int mi = 0; mi < 4; ++mi)                                           \
            _Pragma("unroll")                                                    \
            for (int ei = 0; ei < 8; ++ei)                                       \
                acc[mi][ei] += xv[mi].x * wv4[ei].x + xv[mi].y * wv4[ei].y +     \
                               xv[mi].z * wv4[ei].z + xv[mi].w * wv4[ei].w;      \
    }

template <class LD>
__device__ __forceinline__ void score_body(LD xld, LD rwld,
                                           float* xs /*2*8*68*/, float* wt /*2*64*68*/,
                                           float* sc /*8*65*/,
                                           float* out, float* wsW,
                                           int* wsCnt, int* wsList) {
    const int tid = threadIdx.x;
    const size_t t0 = (size_t)blockIdx.x * 8;
    const int wv = tid >> 6;
    const int lane = tid & 63;
    const int tg = lane & 1;
    const int eg = (lane >> 1) & 7;
    const int kql = (lane >> 4) & 3;
    const int dd = 4 * kql + 16 * wv;
    const int kc0 = blockIdx.x & 15;   // rotated K start

    const int sm = tid >> 4;            // staging roles (coalesced)
    const int sd4 = (tid & 15) * 4;

    float acc[4][8];
#pragma unroll
    for (int mi = 0; mi < 4; ++mi)
#pragma unroll
        for (int ei = 0; ei < 8; ++ei) acc[mi][ei] = 0.f;

    float4 px[3];
    float4 pw[3][4];

    // prologue: issue chunks 0,1,2 into sets 0,1,2; stage chunk 0 to buf0.
    SC_ISSUE(0, 0);
    SC_ISSUE(1, 1);
    SC_ISSUE(2, 2);
    SC_WRITEBUF(0, 0);
    __syncthreads();

#pragma unroll
    for (int i = 0; i < 16; ++i) {
        if (i < 15) SC_WRITEBUF((i + 1) & 1, (i + 1) % 3);  // stage chunk i+1
        if (i < 13) SC_ISSUE(i + 3, i % 3);                  // prefetch chunk i+3
        SC_COMPUTE(i & 1);                                   // compute chunk i
        __syncthreads();
    }

    // in-wave k-quad reduce (deterministic tree over kql)
#pragma unroll
    for (int mi = 0; mi < 4; ++mi)
#pragma unroll
        for (int ei = 0; ei < 8; ++ei) {
            float v = acc[mi][ei];
            v += __shfl_xor(v, 16, 64);
            v += __shfl_xor(v, 32, 64);
            acc[mi][ei] = v;
        }

    // cross-wave reduce: sequential wave phases (deterministic order)
    for (int w = 0; w < 4; ++w) {
        if (wv == w && kql == 0) {
#pragma unroll
            for (int mi = 0; mi < 4; ++mi)
#pragma unroll
                for (int ei = 0; ei < 8; ++ei) {
                    int idx = (tg + 2 * mi) * 65 + eg + 8 * ei;
                    sc[idx] = (w == 0) ? acc[mi][ei] : sc[idx] + acc[mi][ei];
                }
        }
        __syncthreads();
    }

    if (tid < 8) {
        const float* s = &sc[tid * 65];
        float best = -1e30f, secv = -1e30f;
        int bi = 0, si = 0;
        for (int j = 0; j < NEXP; ++j) {
            float v = s[j];
            if (v > best) { secv = best; si = bi; best = v; bi = j; }
            else if (v > secv) { secv = v; si = j; }
        }
        float w0 = 1.0f / (1.0f + expf(secv - best));
        float w1 = 1.0f - w0;
        size_t t = t0 + tid;
        out[OUT_IDX_OFF + t * 2 + 0] = (float)bi;
        out[OUT_IDX_OFF + t * 2 + 1] = (float)si;
        out[OUT_W_OFF + t * 2 + 0] = w0;
        out[OUT_W_OFF + t * 2 + 1] = w1;
        wsW[t * 2 + 0] = w0;
        wsW[t * 2 + 1] = w1;
        int p0 = atomicAdd(&wsCnt[bi], 1);
        if (p0 < LCAP) wsList[bi * LCAP + p0] = (int)(t * 2 + 0);
        int p1 = atomicAdd(&wsCnt[si], 1);
        if (p1 < LCAP) wsList[si * LCAP + p1] = (int)(t * 2 + 1);
    }
}

__global__ __launch_bounds__(256, 2) void score_topk(const void* x, const void* rw,
                                                     float* out, float* wsW,
                                                     int* wsCnt, int* wsList) {
    __shared__ float xs[2 * 8 * 68];
    __shared__ float wt[2 * 64 * 68];
    __shared__ float sc[8 * 65];
    __shared__ int dc;
    int f = detect_f32((const u16*)x, &dc);
    if (f)
        score_body(LdF32{(const float*)x}, LdF32{(const float*)rw}, xs, wt, sc, out, wsW, wsCnt, wsList);
    else
        score_body(LdBF{(const u16*)x}, LdBF{(const u16*)rw}, xs, wt, sc, out, wsW, wsCnt, wsList);
}

// ---------------- Kernel B: per-expert bf16 MFMA GEMM, K-eighth persist-B --
// 512 blocks: e = bid>>3, oct = bid&7; k window [oct*128, oct*128+128).
// Stage B eighth ONCE (1 slab [64r][68 u32], 17KB; proven layout/indexing);
// preload expert token list to LDS (<=4KB). Tile loop over 16-row tiles:
// A stage 16x128 (2 float4/thread, register-prefetched one tile ahead),
// 4 MFMA, plain stores of raw partials to P[t2*512 + oct*64 + col].
// No atomics; every P cell written exactly once. LDS ~26KB -> 2 blocks/CU.
template <class LD>
__device__ __forceinline__ void egemm_body(LD xld, LD nld,
                                           const int* wsCnt, const int* wsList,
                                           float* P,
                                           u16* Ab /*16*136*/, u16* Bb /*64*136*/,
                                           int* eL /*1024*/) {
    const int tid = threadIdx.x;
    const int e = blockIdx.x >> 3;
    const int oct = blockIdx.x & 7;
    const int cntE = min(wsCnt[e], LCAP);
    if (cntE <= 0) return;                       // uniform exit
    const int wv = tid >> 6;
    const int lane = tid & 63;
    const int l15 = lane & 15, quad = lane >> 4;
    const size_t nbase = (size_t)e * (DDIM * RDIM);
    const int k0 = oct * 128;

    // preload this expert's token list (read-only afterwards)
    for (int j = tid; j < cntE; j += 256) eL[j] = wsList[e * LCAP + j];

    // stage B eighth once: 128k x 64r; rq=tid&15 (col group), kp=(tid>>4)+16h
    {
        const int rq = tid & 15;
        const int kpB = tid >> 4;
        u32* bb = (u32*)Bb;
#pragma unroll
        for (int h = 0; h < 4; ++h) {
            int kp = kpB + h * 16;
            float4 g0 = nld.ld4(nbase + (size_t)(k0 + 2 * kp) * RDIM + rq * 4);
            float4 g1 = nld.ld4(nbase + (size_t)(k0 + 2 * kp + 1) * RDIM + rq * 4);
            bb[(rq * 4 + 0) * 68 + kp] = pack2(g0.x, g1.x);
            bb[(rq * 4 + 1) * 68 + kp] = pack2(g0.y, g1.y);
            bb[(rq * 4 + 2) * 68 + kp] = pack2(g0.z, g1.z);
            bb[(rq * 4 + 3) * 68 + kp] = pack2(g0.w, g1.w);
        }
    }
    __syncthreads();                              // Bb + eL visible

    const int rowA = tid >> 4;
    const int kqA = tid & 15;
    const int ntiles = (cntE + 15) >> 4;

    // prologue: tile 0 A-loads
    float4 a0, a1;
    {
        int t2r = eL[min(rowA, cntE - 1)];
        size_t xrow = (size_t)(t2r >> 1) * DDIM + k0;
        a0 = xld.ld4(xrow + kqA * 8);
        a1 = xld.ld4(xrow + kqA * 8 + 4);
    }

    for (int ti = 0; ti < ntiles; ++ti) {
        const int base = ti * 16;
        const int valid = min(16, cntE - base);
        if (ti > 0) __syncthreads();             // prev MFMA reads of Ab done
        {
            uint4 w;
            w.x = pack2(a0.x, a0.y);
            w.y = pack2(a0.z, a0.w);
            w.z = pack2(a1.x, a1.y);
            w.w = pack2(a1.z, a1.w);
            *(uint4*)&((u32*)Ab)[rowA * 68 + kqA * 4] = w;
        }
        __syncthreads();                         // Ab ready
        if (ti + 1 < ntiles) {                   // prefetch next tile's A
            int t2r = eL[min(base + 16 + rowA, cntE - 1)];
            size_t xrow = (size_t)(t2r >> 1) * DDIM + k0;
            a0 = xld.ld4(xrow + kqA * 8);
            a1 = xld.ld4(xrow + kqA * 8 + 4);
        }

        f32x4 acc = {0.f, 0.f, 0.f, 0.f};
#pragma unroll
        for (int ko = 0; ko < 4; ++ko) {
            int kofs = ko * 32 + quad * 8;
            short8 bfr = *(const short8*)&Bb[(16 * wv + l15) * 136 + kofs];
            short8 af = *(const short8*)&Ab[l15 * 136 + kofs];
            acc = __builtin_amdgcn_mfma_f32_16x16x32_bf16(af, bfr, acc, 0, 0, 0);
        }

        // D: row (token m) = quad*4+reg, col r = 16*wv + l15 -> raw partial
#pragma unroll
        for (int reg = 0; reg < 4; ++reg) {
            int m = quad * 4 + reg;
            if (m < valid) {
                int t2 = eL[base + m];
                P[(size_t)t2 * 512 + oct * 64 + 16 * wv + l15] = acc[reg];
            }
        }
    }
}

__global__ __launch_bounds__(256, 2) void expert_gemm(const void* x, const void* neurons,
                                                      const int* wsCnt, const int* wsList,
                                                      float* P) {
    __shared__ u16 Ab[16 * 136];
    __shared__ u16 Bb[64 * 136];
    __shared__ int eL[LCAP];
    __shared__ int dc;
    int f = detect_f32((const u16*)x, &dc);
    if (f)
        egemm_body(LdF32{(const float*)x}, LdF32{(const float*)neurons}, wsCnt, wsList, P, Ab, Bb, eL);
    else
        egemm_body(LdBF{(const u16*)x}, LdBF{(const u16*)neurons}, wsCnt, wsList, P, Ab, Bb, eL);
}

// ---------------- Kernel C: combine partials -------------------------------
// out[t][r] = sum_s wsW[2t+s] * sum_oct P[(2t+s)*512 + oct*64 + r].
// 1024 blocks x 256 thr; 1 element/thread; fully coalesced 256B segments.
__global__ __launch_bounds__(256) void combine(const float* P, const float* wsW,
                                               float* out) {
    int i = blockIdx.x * 256 + threadIdx.x;      // [0, 262144)
    int t = i >> 6, r = i & 63;
    const float* p0 = P + (size_t)(2 * t) * 512 + r;
    const float* p1 = P + (size_t)(2 * t + 1) * 512 + r;
    float s0 = 0.f, s1 = 0.f;
#pragma unroll
    for (int o = 0; o < 8; ++o) {
        s0 += p0[o * 64];
        s1 += p1[o * 64];
    }
    out[i] = wsW[2 * t] * s0 + wsW[2 * t + 1] * s1;
}

extern "C" void kernel_launch(void* const* d_in, const int* in_sizes, int n_in,
                              void* d_out, int out_size, void* d_ws, size_t ws_size,
                              hipStream_t stream) {
    const void* x = d_in[0];
    const void* rw = d_in[1];
    const void* neurons = d_in[2];
    float* out = (float*)d_out;

    char* wsc = (char*)d_ws;
    float* wsW = (float*)wsc;                                  // 32 KB
    int* wsCnt = (int*)(wsc + 32 * 1024);                      // 256 B
    int* wsList = (int*)((char*)wsCnt + 256);                  // 256 KB
    float* P = (float*)(wsc + (1 << 20));                      // 16 MB @ +1MB

    hipMemsetAsync(wsCnt, 0, 256, stream);
    score_topk<<<512, 256, 0, stream>>>(x, rw, out, wsW, wsCnt, wsList);
    expert_gemm<<<512, 256, 0, stream>>>(x, neurons, wsCnt, wsList, P);
    combine<<<1024, 256, 0, stream>>>(P, wsW, out);
}

// Round 7
// 125.400 us; speedup vs baseline: 2.3328x; 2.3328x over previous
//
#include <hip/hip_runtime.h>
#include <hip/hip_bf16.h>

// B=2,S=2048 -> T=4096 tokens; D=1024; N=64 experts; R=64; TOP_K=2.
// Inputs runtime-detected f32 vs bf16 (measured: f32). Outputs f32 flat:
// [0,262144) proj; [262144,270336) idx; [270336,278528) w.
// R16: R15's 3-deep register pipeline SPILLED (VGPR 128, WRITE_SIZE 323MB of
// scratch traffic, 208us). Lesson: deepen parallelism with BLOCKS not
// registers. This round: score compute core reverted byte-identical to the
// R14-proven build (60 VGPR, 43us), K split across blocks instead:
//  - 1024 blocks = 512 token-groups x 2 K-halves; 8 chunks/block (staging
//    scales with K => per-block cost halves, total unchanged); 4 blocks/CU.
//    Partial scores stored to Sb[kh][t][e] (each cell written once).
//  - new topk kernel (16 blocks): half0+half1 (2-addend fl-sum, order-
//    independent), top2+softmax+outputs+expert lists.
//  - egemm/combine unchanged from the passing R14 build.
// Harness d_ws poison fill (~44us) untouchable.
// d_ws: f32 w[8192] (32KB); int cnt[64]; int list[64*1024] (256KB);
//       Sb f32[2][4096][64] @ +1MB (2MB); P f32[8192][8][64] @ +4MB (16MB).

typedef unsigned short u16;
typedef unsigned int u32;
typedef __attribute__((ext_vector_type(8))) short short8;
typedef __attribute__((ext_vector_type(4))) float f32x4;

__device__ __forceinline__ float bf2f(u16 u) {
    u32 v = ((u32)u) << 16; float f; __builtin_memcpy(&f, &v, 4); return f;
}
__device__ __forceinline__ u16 f2bf(float f) {  // RNE
    u32 u; __builtin_memcpy(&u, &f, 4);
    u32 r = u + 0x7fff + ((u >> 16) & 1);
    return (u16)(r >> 16);
}
__device__ __forceinline__ u32 pack2(float a, float b) {
    return ((u32)f2bf(b) << 16) | (u32)f2bf(a);
}

#define T_TOKENS 4096
#define DDIM 1024
#define NEXP 64
#define RDIM 64
#define LCAP 1024
#define OUT_IDX_OFF 262144
#define OUT_W_OFF 270336

struct LdBF {
    const u16* p;
    __device__ __forceinline__ float4 ld4(size_t i) const {
        ushort4 v = *(const ushort4*)(p + i);
        return make_float4(bf2f(v.x), bf2f(v.y), bf2f(v.z), bf2f(v.w));
    }
    __device__ __forceinline__ float ld1(size_t i) const { return bf2f(p[i]); }
};
struct LdF32 {
    const float* p;
    __device__ __forceinline__ float4 ld4(size_t i) const { return *(const float4*)(p + i); }
    __device__ __forceinline__ float ld1(size_t i) const { return p[i]; }
};

// in-block dtype probe: 1 if f32, 0 if bf16 (all blocks same verdict).
__device__ __forceinline__ int detect_f32(const u16* x, int* lds_cnt) {
    if (threadIdx.x == 0) *lds_cnt = 0;
    __syncthreads();
    if (threadIdx.x < 256) {
        unsigned e = (x[threadIdx.x] >> 7) & 0xFF;
        if (e >= 0x68 && e <= 0x88) atomicAdd(lds_cnt, 1);
    }
    __syncthreads();
    int f = (*lds_cnt < 200) ? 1 : 0;
    __syncthreads();
    return f;
}

// ---------------- Kernel A: score GEMM partials (K-split) ------------------
// 1024 blocks x 256 thr: g=bid>>1 (tokens [8g,8g+8)), kh=bid&1 (k half
// [512kh,512kh+512)). 8 K-chunks of 64, order rotated by bid&7. Compute
// core identical to the R14-proven 43us build (1-deep register prefetch,
// 2 barriers/chunk, 60 VGPR -- R15's deeper pipeline spilled). Partial
// scores written to Sb[kh*4096 + t][e]; top2 moved to its own kernel.
// Lane: tg=lane&1 (tokens tg+2mi, mi<4), eg=(lane>>1)&7 (experts eg+8ei,
// ei<8), kql=(lane>>4)&3; k-quad per chunk dd = 4*kql + 16*wv (proven).
template <class LD>
__device__ __forceinline__ void score_body(LD xld, LD rwld,
                                           float* xs /*8*68*/, float* wt /*64*68*/,
                                           float* sc /*8*65*/, float* Sb) {
    const int tid = threadIdx.x;
    const int g = blockIdx.x >> 1;
    const int kh = blockIdx.x & 1;
    const size_t t0 = (size_t)g * 8;
    const int kbase = kh * 512;
    const int wv = tid >> 6;
    const int lane = tid & 63;
    const int tg = lane & 1;
    const int eg = (lane >> 1) & 7;
    const int kql = (lane >> 4) & 3;
    const int dd = 4 * kql + 16 * wv;
    const int kc0 = blockIdx.x & 7;    // rotated chunk start (8 chunks)

    const int sm = tid >> 4;            // staging roles (coalesced)
    const int sd4 = (tid & 15) * 4;

    float acc[4][8];
#pragma unroll
    for (int mi = 0; mi < 4; ++mi)
#pragma unroll
        for (int ei = 0; ei < 8; ++ei) acc[mi][ei] = 0.f;

    float4 px;
    if (tid < 128) px = xld.ld4((t0 + sm) * DDIM + kbase + kc0 * 64 + sd4);
    float4 pw[4];
#pragma unroll
    for (int h = 0; h < 4; ++h) {
        int i4 = tid + h * 256;
        pw[h] = rwld.ld4((size_t)(i4 >> 4) * DDIM + kbase + kc0 * 64 + (i4 & 15) * 4);
    }

    for (int i = 0; i < 8; ++i) {
        if (i > 0) __syncthreads();
        if (tid < 128) *(float4*)&xs[sm * 68 + sd4] = px;
#pragma unroll
        for (int h = 0; h < 4; ++h) {
            int i4 = tid + h * 256;
            *(float4*)&wt[(i4 >> 4) * 68 + (i4 & 15) * 4] = pw[h];
        }
        __syncthreads();

        if (i < 7) {
            int kn = kbase + ((i + 1 + kc0) & 7) * 64;
            if (tid < 128) px = xld.ld4((t0 + sm) * DDIM + kn + sd4);
#pragma unroll
            for (int h = 0; h < 4; ++h) {
                int i4 = tid + h * 256;
                pw[h] = rwld.ld4((size_t)(i4 >> 4) * DDIM + kn + (i4 & 15) * 4);
            }
        }

        float4 xv[4], wv4[8];
#pragma unroll
        for (int mi = 0; mi < 4; ++mi)
            xv[mi] = *(const float4*)&xs[(tg + 2 * mi) * 68 + dd];
#pragma unroll
        for (int ei = 0; ei < 8; ++ei)
            wv4[ei] = *(const float4*)&wt[(eg + 8 * ei) * 68 + dd];
#pragma unroll
        for (int mi = 0; mi < 4; ++mi)
#pragma unroll
            for (int ei = 0; ei < 8; ++ei)
                acc[mi][ei] += xv[mi].x * wv4[ei].x + xv[mi].y * wv4[ei].y +
                               xv[mi].z * wv4[ei].z + xv[mi].w * wv4[ei].w;
    }

    // in-wave k-quad reduce (deterministic tree over kql)
#pragma unroll
    for (int mi = 0; mi < 4; ++mi)
#pragma unroll
        for (int ei = 0; ei < 8; ++ei) {
            float v = acc[mi][ei];
            v += __shfl_xor(v, 16, 64);
            v += __shfl_xor(v, 32, 64);
            acc[mi][ei] = v;
        }
    __syncthreads();

    // cross-wave reduce: sequential wave phases (deterministic order)
    for (int w = 0; w < 4; ++w) {
        if (wv == w && kql == 0) {
#pragma unroll
            for (int mi = 0; mi < 4; ++mi)
#pragma unroll
                for (int ei = 0; ei < 8; ++ei) {
                    int idx = (tg + 2 * mi) * 65 + eg + 8 * ei;
                    sc[idx] = (w == 0) ? acc[mi][ei] : sc[idx] + acc[mi][ei];
                }
        }
        __syncthreads();
    }

    // store this K-half's partial scores: 8 tokens x 64 experts
    if (tid < 128) {
        int t = tid >> 4, e4 = (tid & 15) * 4;
        const float* s = &sc[t * 65 + e4];
        float4 v = make_float4(s[0], s[1], s[2], s[3]);
        *(float4*)&Sb[((size_t)kh * T_TOKENS + t0 + t) * 64 + e4] = v;
    }
}

__global__ __launch_bounds__(256, 4) void score_part(const void* x, const void* rw,
                                                     float* Sb) {
    __shared__ float xs[8 * 68];
    __shared__ float wt[64 * 68];
    __shared__ float sc[8 * 65];
    __shared__ int dc;
    int f = detect_f32((const u16*)x, &dc);
    if (f)
        score_body(LdF32{(const float*)x}, LdF32{(const float*)rw}, xs, wt, sc, Sb);
    else
        score_body(LdBF{(const u16*)x}, LdBF{(const u16*)rw}, xs, wt, sc, Sb);
}

// ---------------- Kernel A2: top-2 + softmax + outputs + expert lists -----
// 16 blocks x 256 thr; 1 token/thread. score[t][e] = Sb[0][t][e]+Sb[1][t][e]
// (2-addend fl-sum: order-independent => deterministic). Same scan/tie-break
// semantics as reference (strict >, ascending j).
__global__ __launch_bounds__(256) void topk_softmax(const float* Sb, float* out,
                                                    float* wsW, int* wsCnt,
                                                    int* wsList) {
    int t = blockIdx.x * 256 + threadIdx.x;      // [0, 4096)
    const float* s0 = Sb + (size_t)t * 64;
    const float* s1 = Sb + ((size_t)T_TOKENS + t) * 64;
    float best = -1e30f, secv = -1e30f;
    int bi = 0, si = 0;
    for (int j = 0; j < NEXP; j += 4) {
        float4 a = *(const float4*)(s0 + j);
        float4 b = *(const float4*)(s1 + j);
        float v0 = a.x + b.x, v1 = a.y + b.y, v2 = a.z + b.z, v3 = a.w + b.w;
        if (v0 > best) { secv = best; si = bi; best = v0; bi = j; }
        else if (v0 > secv) { secv = v0; si = j; }
        if (v1 > best) { secv = best; si = bi; best = v1; bi = j + 1; }
        else if (v1 > secv) { secv = v1; si = j + 1; }
        if (v2 > best) { secv = best; si = bi; best = v2; bi = j + 2; }
        else if (v2 > secv) { secv = v2; si = j + 2; }
        if (v3 > best) { secv = best; si = bi; best = v3; bi = j + 3; }
        else if (v3 > secv) { secv = v3; si = j + 3; }
    }
    float w0 = 1.0f / (1.0f + expf(secv - best));
    float w1 = 1.0f - w0;
    out[OUT_IDX_OFF + (size_t)t * 2 + 0] = (float)bi;
    out[OUT_IDX_OFF + (size_t)t * 2 + 1] = (float)si;
    out[OUT_W_OFF + (size_t)t * 2 + 0] = w0;
    out[OUT_W_OFF + (size_t)t * 2 + 1] = w1;
    wsW[t * 2 + 0] = w0;
    wsW[t * 2 + 1] = w1;
    int p0 = atomicAdd(&wsCnt[bi], 1);
    if (p0 < LCAP) wsList[bi * LCAP + p0] = t * 2 + 0;
    int p1 = atomicAdd(&wsCnt[si], 1);
    if (p1 < LCAP) wsList[si * LCAP + p1] = t * 2 + 1;
}

// ---------------- Kernel B: per-expert bf16 MFMA GEMM, K-eighth persist-B --
// 512 blocks: e = bid>>3, oct = bid&7; k window [oct*128, oct*128+128).
// Stage B eighth ONCE (1 slab [64r][68 u32], 17KB; proven layout/indexing);
// preload expert token list to LDS (<=4KB). Tile loop over 16-row tiles:
// A stage 16x128 (2 float4/thread, register-prefetched one tile ahead),
// 4 MFMA, plain stores of raw partials to P[t2*512 + oct*64 + col].
// No atomics; every P cell written exactly once. LDS ~26KB -> 2 blocks/CU.
template <class LD>
__device__ __forceinline__ void egemm_body(LD xld, LD nld,
                                           const int* wsCnt, const int* wsList,
                                           float* P,
                                           u16* Ab /*16*136*/, u16* Bb /*64*136*/,
                                           int* eL /*1024*/) {
    const int tid = threadIdx.x;
    const int e = blockIdx.x >> 3;
    const int oct = blockIdx.x & 7;
    const int cntE = min(wsCnt[e], LCAP);
    if (cntE <= 0) return;                       // uniform exit
    const int wv = tid >> 6;
    const int lane = tid & 63;
    const int l15 = lane & 15, quad = lane >> 4;
    const size_t nbase = (size_t)e * (DDIM * RDIM);
    const int k0 = oct * 128;

    // preload this expert's token list (read-only afterwards)
    for (int j = tid; j < cntE; j += 256) eL[j] = wsList[e * LCAP + j];

    // stage B eighth once: 128k x 64r; rq=tid&15 (col group), kp=(tid>>4)+16h
    {
        const int rq = tid & 15;
        const int kpB = tid >> 4;
        u32* bb = (u32*)Bb;
#pragma unroll
        for (int h = 0; h < 4; ++h) {
            int kp = kpB + h * 16;
            float4 g0 = nld.ld4(nbase + (size_t)(k0 + 2 * kp) * RDIM + rq * 4);
            float4 g1 = nld.ld4(nbase + (size_t)(k0 + 2 * kp + 1) * RDIM + rq * 4);
            bb[(rq * 4 + 0) * 68 + kp] = pack2(g0.x, g1.x);
            bb[(rq * 4 + 1) * 68 + kp] = pack2(g0.y, g1.y);
            bb[(rq * 4 + 2) * 68 + kp] = pack2(g0.z, g1.z);
            bb[(rq * 4 + 3) * 68 + kp] = pack2(g0.w, g1.w);
        }
    }
    __syncthreads();                              // Bb + eL visible

    const int rowA = tid >> 4;
    const int kqA = tid & 15;
    const int ntiles = (cntE + 15) >> 4;

    // prologue: tile 0 A-loads
    float4 a0, a1;
    {
        int t2r = eL[min(rowA, cntE - 1)];
        size_t xrow = (size_t)(t2r >> 1) * DDIM + k0;
        a0 = xld.ld4(xrow + kqA * 8);
        a1 = xld.ld4(xrow + kqA * 8 + 4);
    }

    for (int ti = 0; ti < ntiles; ++ti) {
        const int base = ti * 16;
        const int valid = min(16, cntE - base);
        if (ti > 0) __syncthreads();             // prev MFMA reads of Ab done
        {
            uint4 w;
            w.x = pack2(a0.x, a0.y);
            w.y = pack2(a0.z, a0.w);
            w.z = pack2(a1.x, a1.y);
            w.w = pack2(a1.z, a1.w);
            *(uint4*)&((u32*)Ab)[rowA * 68 + kqA * 4] = w;
        }
        __syncthreads();                         // Ab ready
        if (ti + 1 < ntiles) {                   // prefetch next tile's A
            int t2r = eL[min(base + 16 + rowA, cntE - 1)];
            size_t xrow = (size_t)(t2r >> 1) * DDIM + k0;
            a0 = xld.ld4(xrow + kqA * 8);
            a1 = xld.ld4(xrow + kqA * 8 + 4);
        }

        f32x4 acc = {0.f, 0.f, 0.f, 0.f};
#pragma unroll
        for (int ko = 0; ko < 4; ++ko) {
            int kofs = ko * 32 + quad * 8;
            short8 bfr = *(const short8*)&Bb[(16 * wv + l15) * 136 + kofs];
            short8 af = *(const short8*)&Ab[l15 * 136 + kofs];
            acc = __builtin_amdgcn_mfma_f32_16x16x32_bf16(af, bfr, acc, 0, 0, 0);
        }

        // D: row (token m) = quad*4+reg, col r = 16*wv + l15 -> raw partial
#pragma unroll
        for (int reg = 0; reg < 4; ++reg) {
            int m = quad * 4 + reg;
            if (m < valid) {
                int t2 = eL[base + m];
                P[(size_t)t2 * 512 + oct * 64 + 16 * wv + l15] = acc[reg];
            }
        }
    }
}

__global__ __launch_bounds__(256, 2) void expert_gemm(const void* x, const void* neurons,
                                                      const int* wsCnt, const int* wsList,
                                                      float* P) {
    __shared__ u16 Ab[16 * 136];
    __shared__ u16 Bb[64 * 136];
    __shared__ int eL[LCAP];
    __shared__ int dc;
    int f = detect_f32((const u16*)x, &dc);
    if (f)
        egemm_body(LdF32{(const float*)x}, LdF32{(const float*)neurons}, wsCnt, wsList, P, Ab, Bb, eL);
    else
        egemm_body(LdBF{(const u16*)x}, LdBF{(const u16*)neurons}, wsCnt, wsList, P, Ab, Bb, eL);
}

// ---------------- Kernel C: combine partials -------------------------------
// out[t][r] = sum_s wsW[2t+s] * sum_oct P[(2t+s)*512 + oct*64 + r].
// 1024 blocks x 256 thr; 1 element/thread; fully coalesced 256B segments.
__global__ __launch_bounds__(256) void combine(const float* P, const float* wsW,
                                               float* out) {
    int i = blockIdx.x * 256 + threadIdx.x;      // [0, 262144)
    int t = i >> 6, r = i & 63;
    const float* p0 = P + (size_t)(2 * t) * 512 + r;
    const float* p1 = P + (size_t)(2 * t + 1) * 512 + r;
    float s0 = 0.f, s1 = 0.f;
#pragma unroll
    for (int o = 0; o < 8; ++o) {
        s0 += p0[o * 64];
        s1 += p1[o * 64];
    }
    out[i] = wsW[2 * t] * s0 + wsW[2 * t + 1] * s1;
}

extern "C" void kernel_launch(void* const* d_in, const int* in_sizes, int n_in,
                              void* d_out, int out_size, void* d_ws, size_t ws_size,
                              hipStream_t stream) {
    const void* x = d_in[0];
    const void* rw = d_in[1];
    const void* neurons = d_in[2];
    float* out = (float*)d_out;

    char* wsc = (char*)d_ws;
    float* wsW = (float*)wsc;                                  // 32 KB
    int* wsCnt = (int*)(wsc + 32 * 1024);                      // 256 B
    int* wsList = (int*)((char*)wsCnt + 256);                  // 256 KB
    float* Sb = (float*)(wsc + (1 << 20));                     // 2 MB @ +1MB
    float* P = (float*)(wsc + (4 << 20));                      // 16 MB @ +4MB

    hipMemsetAsync(wsCnt, 0, 256, stream);
    score_part<<<1024, 256, 0, stream>>>(x, rw, Sb);
    topk_softmax<<<16, 256, 0, stream>>>(Sb, out, wsW, wsCnt, wsList);
    expert_gemm<<<512, 256, 0, stream>>>(x, neurons, wsCnt, wsList, P);
    combine<<<1024, 256, 0, stream>>>(P, wsW, out);
}